// Round 1
// baseline (903.458 us; speedup 1.0000x reference)
//
#include <hip/hip_runtime.h>
#include <hip/hip_bf16.h>

// Problem constants (B=4, S=2048, H=2048, E=8, K=2)
#define T_TOK 8192
#define H_DIM 2048
#define NE 8
#define NT (H_DIM / 64)   // 32 K-tiles of 64

typedef float f32x4 __attribute__((ext_vector_type(4)));
typedef short s16x8 __attribute__((ext_vector_type(8)));

typedef __attribute__((address_space(3))) unsigned int lds_uint;
typedef __attribute__((address_space(1))) const unsigned int glob_uint;

static __device__ __forceinline__ void async_ld16(const void* g, void* l) {
    // 64 lanes x 16B: global per-lane address -> LDS (wave-uniform base + lane*16)
    __builtin_amdgcn_global_load_lds((glob_uint*)g, (lds_uint*)l, 16, 0, 0);
}

static __device__ __forceinline__ unsigned short f32_to_bf16(float f) {
    unsigned int u = __builtin_bit_cast(unsigned int, f);
    unsigned int r = (u + 0x7FFFu + ((u >> 16) & 1u)) >> 16;
    return (unsigned short)r;
}

// ---------------------------------------------------------------------------
// Kernel 1: convert W fp32 -> bf16, zero expert counters. (unchanged)
// ---------------------------------------------------------------------------
__global__ __launch_bounds__(256) void prep_kernel(
        const float* __restrict__ w, unsigned short* __restrict__ wb,
        int* __restrict__ cnt) {
    const long g = (long)blockIdx.x * 256 + threadIdx.x;
    if (g < NE) cnt[g] = 0;
    const long nt = (long)gridDim.x * 256;
    const long N_W4 = (long)NE * H_DIM * H_DIM / 4;  // 8,388,608 float4
    const float4* w4 = (const float4*)w;
    ushort4* wb4 = (ushort4*)wb;
    for (long i = g; i < N_W4; i += nt) {
        float4 v = w4[i];
        wb4[i] = make_ushort4(f32_to_bf16(v.x), f32_to_bf16(v.y),
                              f32_to_bf16(v.z), f32_to_bf16(v.w));
    }
}

// ---------------------------------------------------------------------------
// Kernel 2: router (unchanged). 512 blocks x 16 tokens, fused X fp32->bf16,
// fp32 logits, softmax-free top-2, per-block aggregated list append.
// ---------------------------------------------------------------------------
__global__ __launch_bounds__(256) void router_kernel(
        const float* __restrict__ x, const float* __restrict__ gate,
        unsigned short* __restrict__ xb, float* __restrict__ logits,
        int* __restrict__ cnt, int* __restrict__ list, float* __restrict__ wl) {
    __shared__ float4 gs[NE * H_DIM / 4];  // 64 KiB
    __shared__ int aExp[32];
    __shared__ float aW[32];
    const float4* g4 = (const float4*)gate;
    for (int i = threadIdx.x; i < NE * H_DIM / 4; i += 256) gs[i] = g4[i];
    __syncthreads();

    const int wave = threadIdx.x >> 6, lane = threadIdx.x & 63;

    for (int it = 0; it < 4; ++it) {
        const int tok = wave * 4 + it;               // 0..15 within block
        const int t = blockIdx.x * 16 + tok;
        const float4* xr = (const float4*)(x + (long)t * H_DIM);
        ushort4* xw = (ushort4*)(xb + (long)t * H_DIM);
        float acc[NE];
#pragma unroll
        for (int e = 0; e < NE; ++e) acc[e] = 0.f;
#pragma unroll
        for (int i = 0; i < 8; ++i) {
            float4 xv = xr[i * 64 + lane];
            xw[i * 64 + lane] = make_ushort4(f32_to_bf16(xv.x), f32_to_bf16(xv.y),
                                             f32_to_bf16(xv.z), f32_to_bf16(xv.w));
#pragma unroll
            for (int e = 0; e < NE; ++e) {
                float4 gv = gs[e * 512 + i * 64 + lane];
                acc[e] += xv.x * gv.x + xv.y * gv.y + xv.z * gv.z + xv.w * gv.w;
            }
        }
#pragma unroll
        for (int e = 0; e < NE; ++e)
#pragma unroll
            for (int off = 32; off > 0; off >>= 1)
                acc[e] += __shfl_xor(acc[e], off, 64);

        if (lane == 0) {
            float l0 = -1e30f; int i0 = 0;
#pragma unroll
            for (int e = 0; e < NE; ++e)
                if (acc[e] > l0) { l0 = acc[e]; i0 = e; }
            float l1 = -1e30f; int i1 = 0;
#pragma unroll
            for (int e = 0; e < NE; ++e)
                if (e != i0 && acc[e] > l1) { l1 = acc[e]; i1 = e; }
            float e1v = __expf(l1 - l0);
            float inv = 1.f / (1.f + e1v);
#pragma unroll
            for (int e = 0; e < NE; ++e) logits[(long)t * NE + e] = acc[e];
            aExp[tok * 2] = i0;     aW[tok * 2] = inv;
            aExp[tok * 2 + 1] = i1; aW[tok * 2 + 1] = e1v * inv;
        }
    }
    __syncthreads();

    if (threadIdx.x < NE) {
        const int e = threadIdx.x;
        int c = 0;
#pragma unroll
        for (int k = 0; k < 32; ++k) c += (aExp[k] == e);
        if (c) {
            int pos = atomicAdd(&cnt[e], c);
            for (int k = 0; k < 32; ++k)
                if (aExp[k] == e) {
                    list[e * T_TOK + pos] = blockIdx.x * 16 + (k >> 1);
                    wl[e * T_TOK + pos] = aW[k];
                    ++pos;
                }
        }
    }
}

// ---------------------------------------------------------------------------
// Kernel 3: grouped expert GEMM — 256x256 tile, BK=64, 8 waves (2Mx4N),
// double-buffered LDS (128 KiB), counted-vmcnt deep pipeline (T3+T4),
// setprio around MFMA clusters (T5), XOR-swizzled LDS (T2, kept).
//
// LDS layout per buffer: 256 rows x 64 bf16 = 2048 16B-chunks. Logical
// (row r, k-chunk c) lives at phys chunk (r<<3)|(c^(r&7)). global_load_lds
// writes phys-linear, so each lane fetches the global column matching its
// phys slot: c = (p&7)^(r&7) (involution). ds_read_b128 per 16-lane quarter
// then covers all 32 banks exactly -> conflict-free.
//
// Pipeline invariant (per wave, 8 gload_lds per K-tile):
//   boundary of tile t: issue 6 loads of tile t+1, then s_waitcnt vmcnt(6)
//   -> the 8 oldest (all of tile t) retired, 6 stay in flight across the
//   barrier; phase 0 issues the remaining 2. Only the last tile drains to 0.
// WAR safety: last reads of buf b happen in phase 2; phase 2's post-MFMA
// barrier orders every wave's retired reads before any wave's next-boundary
// stage issues into buf b.
// ---------------------------------------------------------------------------
__global__ __launch_bounds__(512, 2) void moe_gemm(
        const unsigned short* __restrict__ xb, const unsigned short* __restrict__ wb,
        const int* __restrict__ cnt, const int* __restrict__ list,
        const float* __restrict__ wl, float* __restrict__ out) {
    __shared__ uint4 Abuf[2][2048];  // 2 x 32 KiB
    __shared__ uint4 Bbuf[2][2048];  // 2 x 32 KiB
    __shared__ int tIdx[256];
    __shared__ float tw[256];

    const int bx = blockIdx.x;
    const int e  = bx >> 8;          // 256 blocks per expert
    const int ct = (bx >> 5) & 7;    // 8 col tiles of 256
    const int rt = bx & 31;          // up to 32 row tiles of 256
    const int n = cnt[e];
    const int row0 = rt << 8;
    if (row0 >= n) return;
    const int rv = min(256, n - row0);

    const int tid = threadIdx.x;
    if (tid < 256) {
        if (tid < rv) {
            tIdx[tid] = list[e * T_TOK + row0 + tid];
            tw[tid]   = wl[e * T_TOK + row0 + tid];
        } else { tIdx[tid] = 0; tw[tid] = 0.f; }
    }
    __syncthreads();   // full drain: vmcnt==0 before staging begins

    const int wave = tid >> 6, lane = tid & 63;
    const int wm = wave >> 2;        // 0..1  (wave rows: wm*128 .. +127)
    const int wn = wave & 3;         // 0..3  (wave cols: wn*64 .. +63)
    const int quad = lane >> 4, l16 = lane & 15;

    f32x4 acc[8][4];
#pragma unroll
    for (int i = 0; i < 8; ++i)
#pragma unroll
        for (int j = 0; j < 4; ++j) acc[i][j] = (f32x4){0.f, 0.f, 0.f, 0.f};

    // Per-lane pre-swizzled global sources. Per tile: 4 A issues + 4 B issues,
    // issue i covers phys chunks [i*512, (i+1)*512).
    const unsigned short* aSrc[4];
    const unsigned short* bSrc[4];
    const long wbase = (long)e * H_DIM * H_DIM + (long)(ct * 256) * H_DIM;
#pragma unroll
    for (int i = 0; i < 4; ++i) {
        const int p = i * 512 + tid;
        const int r = p >> 3;
        const int c = (p & 7) ^ (r & 7);
        aSrc[i] = xb + (long)tIdx[r] * H_DIM + c * 8;
        bSrc[i] = wb + wbase + (long)r * H_DIM + c * 8;
    }
    uint4* const Ab = &Abuf[0][0];
    uint4* const Bb = &Bbuf[0][0];
    const int dst0 = wave * 64;      // wave-uniform LDS chunk base

    // Prologue: stage tile 0 into buffer 0 (8 loads in flight).
#pragma unroll
    for (int i = 0; i < 4; ++i) async_ld16(aSrc[i], Ab + i * 512 + dst0);
#pragma unroll
    for (int i = 0; i < 4; ++i) async_ld16(bSrc[i], Bb + i * 512 + dst0);

    s16x8 Afr[4][2];      // current A half: 4 m-frags x 2 k-steps
    s16x8 Bfr[2][2][2];   // both B halves: [ns][j][ks] (held all tile)

#pragma unroll 2
    for (int t = 0; t < NT; ++t) {
        const int b = t & 1;
        const s16x8* Ap = (const s16x8*)(Ab + (b << 11));
        const s16x8* Bp = (const s16x8*)(Bb + (b << 11));
        uint4* An = Ab + ((b ^ 1) << 11);
        uint4* Bn = Bb + ((b ^ 1) << 11);
        const int k1 = (t + 1) << 6;

        // ---- tile boundary: prefetch 6/8 of tile t+1, counted wait on tile t
        if (t + 1 < NT) {
#pragma unroll
            for (int i = 0; i < 4; ++i) async_ld16(aSrc[i] + k1, An + i * 512 + dst0);
#pragma unroll
            for (int i = 0; i < 2; ++i) async_ld16(bSrc[i] + k1, Bn + i * 512 + dst0);
            asm volatile("s_waitcnt vmcnt(6)" ::: "memory");
        } else {
            asm volatile("s_waitcnt vmcnt(0)" ::: "memory");
        }
        __builtin_amdgcn_s_barrier();   // tile t fully visible to all waves

        // ---- phase 0: read A(ms=0) + B(ns=0); MFMA quadrant (0,0)
#pragma unroll
        for (int ks = 0; ks < 2; ++ks) {
            const int kc = ks * 4 + quad;
#pragma unroll
            for (int i = 0; i < 4; ++i) {
                const int r = wm * 128 + i * 16 + l16;
                Afr[i][ks] = Ap[(r << 3) | (kc ^ (r & 7))];
            }
#pragma unroll
            for (int j = 0; j < 2; ++j) {
                const int d = wn * 64 + j * 16 + l16;
                Bfr[0][j][ks] = Bp[(d << 3) | (kc ^ (d & 7))];
            }
        }
        if (t + 1 < NT) {   // remaining 2 stage issues for tile t+1
#pragma unroll
            for (int i = 2; i < 4; ++i) async_ld16(bSrc[i] + k1, Bn + i * 512 + dst0);
        }
        __builtin_amdgcn_s_barrier();
        __builtin_amdgcn_s_setprio(1);
#pragma unroll
        for (int ks = 0; ks < 2; ++ks)
#pragma unroll
            for (int i = 0; i < 4; ++i)
#pragma unroll
                for (int j = 0; j < 2; ++j)
                    acc[i][j] = __builtin_amdgcn_mfma_f32_16x16x32_bf16(
                        Afr[i][ks], Bfr[0][j][ks], acc[i][j], 0, 0, 0);
        __builtin_amdgcn_s_setprio(0);
        __builtin_amdgcn_s_barrier();

        // ---- phase 1: read B(ns=1); MFMA quadrant (0,1)
#pragma unroll
        for (int ks = 0; ks < 2; ++ks) {
            const int kc = ks * 4 + quad;
#pragma unroll
            for (int j = 0; j < 2; ++j) {
                const int d = wn * 64 + 32 + j * 16 + l16;
                Bfr[1][j][ks] = Bp[(d << 3) | (kc ^ (d & 7))];
            }
        }
        __builtin_amdgcn_s_barrier();
        __builtin_amdgcn_s_setprio(1);
#pragma unroll
        for (int ks = 0; ks < 2; ++ks)
#pragma unroll
            for (int i = 0; i < 4; ++i)
#pragma unroll
                for (int j = 0; j < 2; ++j)
                    acc[i][2 + j] = __builtin_amdgcn_mfma_f32_16x16x32_bf16(
                        Afr[i][ks], Bfr[1][j][ks], acc[i][2 + j], 0, 0, 0);
        __builtin_amdgcn_s_setprio(0);
        __builtin_amdgcn_s_barrier();

        // ---- phase 2: read A(ms=1); MFMA quadrant (1,0)
#pragma unroll
        for (int ks = 0; ks < 2; ++ks) {
            const int kc = ks * 4 + quad;
#pragma unroll
            for (int i = 0; i < 4; ++i) {
                const int r = wm * 128 + 64 + i * 16 + l16;
                Afr[i][ks] = Ap[(r << 3) | (kc ^ (r & 7))];
            }
        }
        __builtin_amdgcn_s_barrier();
        __builtin_amdgcn_s_setprio(1);
#pragma unroll
        for (int ks = 0; ks < 2; ++ks)
#pragma unroll
            for (int i = 0; i < 4; ++i)
#pragma unroll
                for (int j = 0; j < 2; ++j)
                    acc[4 + i][j] = __builtin_amdgcn_mfma_f32_16x16x32_bf16(
                        Afr[i][ks], Bfr[0][j][ks], acc[4 + i][j], 0, 0, 0);
        __builtin_amdgcn_s_setprio(0);
        __builtin_amdgcn_s_barrier();   // last reads of buf b now globally retired

        // ---- phase 3: MFMA quadrant (1,1) — no reads, no barrier needed
        __builtin_amdgcn_s_setprio(1);
#pragma unroll
        for (int ks = 0; ks < 2; ++ks)
#pragma unroll
            for (int i = 0; i < 4; ++i)
#pragma unroll
                for (int j = 0; j < 2; ++j)
                    acc[4 + i][2 + j] = __builtin_amdgcn_mfma_f32_16x16x32_bf16(
                        Afr[i][ks], Bfr[1][j][ks], acc[4 + i][2 + j], 0, 0, 0);
        __builtin_amdgcn_s_setprio(0);
    }

    // Epilogue: C/D layout col = lane&15, row = quad*4 + reg.
    const int colbase = ct * 256 + wn * 64;
#pragma unroll
    for (int mi = 0; mi < 8; ++mi) {
        const int rbase = wm * 128 + mi * 16 + quad * 4;
#pragma unroll
        for (int jr = 0; jr < 4; ++jr) {
            const int r = rbase + jr;
            if (r < rv) {
                const float wgt = tw[r];
                const long orow = (long)tIdx[r] * H_DIM + colbase;
#pragma unroll
                for (int nj = 0; nj < 4; ++nj)
                    atomicAdd(&out[orow + nj * 16 + l16], acc[mi][nj][jr] * wgt);
            }
        }
    }
}

// ---------------------------------------------------------------------------
extern "C" void kernel_launch(void* const* d_in, const int* in_sizes, int n_in,
                              void* d_out, int out_size, void* d_ws, size_t ws_size,
                              hipStream_t stream) {
    (void)in_sizes; (void)n_in; (void)out_size; (void)ws_size;
    const float* x    = (const float*)d_in[0];   // [T, H] fp32
    const float* gate = (const float*)d_in[1];   // [E, H] fp32
    const float* w    = (const float*)d_in[2];   // [E, H, H] fp32

    float* out    = (float*)d_out;                       // [T, H]
    float* logits = out + (size_t)T_TOK * H_DIM;         // [T, E]

    char* ws = (char*)d_ws;
    unsigned short* xb = (unsigned short*)(ws);                 // 33,554,432 B
    unsigned short* wb = (unsigned short*)(ws + 33554432);      // 67,108,864 B
    int*   cnt  = (int*)(ws + 100663296);                       // 32 B
    int*   list = (int*)(ws + 100663328);                       // 262,144 B
    float* wl   = (float*)(ws + 100925472);                     // 262,144 B

    hipMemsetAsync(out, 0, (size_t)T_TOK * H_DIM * sizeof(float), stream);
    prep_kernel<<<2048, 256, 0, stream>>>(w, wb, cnt);
    router_kernel<<<512, 256, 0, stream>>>(x, gate, xb, logits, cnt, list, wl);
    // 8 experts x 32 row tiles x 8 col tiles = 2048 blocks, 512 threads
    moe_gemm<<<2048, 512, 0, stream>>>(xb, wb, cnt, list, wl, out);
}

// Round 2
// 503.578 us; speedup vs baseline: 1.7941x; 1.7941x over previous
//
#include <hip/hip_runtime.h>
#include <hip/hip_bf16.h>

// Problem constants (B=4, S=2048, H=2048, E=8, K=2)
#define T_TOK 8192
#define H_DIM 2048
#define NE 8
#define NT (H_DIM / 64)   // 32 K-tiles of 64

typedef float f32x4 __attribute__((ext_vector_type(4)));
typedef short s16x8 __attribute__((ext_vector_type(8)));

typedef __attribute__((address_space(3))) unsigned int lds_uint;
typedef __attribute__((address_space(1))) const unsigned int glob_uint;

static __device__ __forceinline__ void async_ld16(const void* g, void* l) {
    // 64 lanes x 16B: global per-lane address -> LDS (wave-uniform base + lane*16)
    __builtin_amdgcn_global_load_lds((glob_uint*)g, (lds_uint*)l, 16, 0, 0);
}

static __device__ __forceinline__ unsigned short f32_to_bf16(float f) {
    unsigned int u = __builtin_bit_cast(unsigned int, f);
    unsigned int r = (u + 0x7FFFu + ((u >> 16) & 1u)) >> 16;
    return (unsigned short)r;
}

// ---------------------------------------------------------------------------
// Kernel 1: convert W fp32 -> bf16, zero expert counters. (unchanged)
// ---------------------------------------------------------------------------
__global__ __launch_bounds__(256) void prep_kernel(
        const float* __restrict__ w, unsigned short* __restrict__ wb,
        int* __restrict__ cnt) {
    const long g = (long)blockIdx.x * 256 + threadIdx.x;
    if (g < NE) cnt[g] = 0;
    const long nt = (long)gridDim.x * 256;
    const long N_W4 = (long)NE * H_DIM * H_DIM / 4;  // 8,388,608 float4
    const float4* w4 = (const float4*)w;
    ushort4* wb4 = (ushort4*)wb;
    for (long i = g; i < N_W4; i += nt) {
        float4 v = w4[i];
        wb4[i] = make_ushort4(f32_to_bf16(v.x), f32_to_bf16(v.y),
                              f32_to_bf16(v.z), f32_to_bf16(v.w));
    }
}

// ---------------------------------------------------------------------------
// Kernel 2: router (unchanged). 512 blocks x 16 tokens, fused X fp32->bf16,
// fp32 logits, softmax-free top-2, per-block aggregated list append.
// ---------------------------------------------------------------------------
__global__ __launch_bounds__(256) void router_kernel(
        const float* __restrict__ x, const float* __restrict__ gate,
        unsigned short* __restrict__ xb, float* __restrict__ logits,
        int* __restrict__ cnt, int* __restrict__ list, float* __restrict__ wl) {
    __shared__ float4 gs[NE * H_DIM / 4];  // 64 KiB
    __shared__ int aExp[32];
    __shared__ float aW[32];
    const float4* g4 = (const float4*)gate;
    for (int i = threadIdx.x; i < NE * H_DIM / 4; i += 256) gs[i] = g4[i];
    __syncthreads();

    const int wave = threadIdx.x >> 6, lane = threadIdx.x & 63;

    for (int it = 0; it < 4; ++it) {
        const int tok = wave * 4 + it;               // 0..15 within block
        const int t = blockIdx.x * 16 + tok;
        const float4* xr = (const float4*)(x + (long)t * H_DIM);
        ushort4* xw = (ushort4*)(xb + (long)t * H_DIM);
        float acc[NE];
#pragma unroll
        for (int e = 0; e < NE; ++e) acc[e] = 0.f;
#pragma unroll
        for (int i = 0; i < 8; ++i) {
            float4 xv = xr[i * 64 + lane];
            xw[i * 64 + lane] = make_ushort4(f32_to_bf16(xv.x), f32_to_bf16(xv.y),
                                             f32_to_bf16(xv.z), f32_to_bf16(xv.w));
#pragma unroll
            for (int e = 0; e < NE; ++e) {
                float4 gv = gs[e * 512 + i * 64 + lane];
                acc[e] += xv.x * gv.x + xv.y * gv.y + xv.z * gv.z + xv.w * gv.w;
            }
        }
#pragma unroll
        for (int e = 0; e < NE; ++e)
#pragma unroll
            for (int off = 32; off > 0; off >>= 1)
                acc[e] += __shfl_xor(acc[e], off, 64);

        if (lane == 0) {
            float l0 = -1e30f; int i0 = 0;
#pragma unroll
            for (int e = 0; e < NE; ++e)
                if (acc[e] > l0) { l0 = acc[e]; i0 = e; }
            float l1 = -1e30f; int i1 = 0;
#pragma unroll
            for (int e = 0; e < NE; ++e)
                if (e != i0 && acc[e] > l1) { l1 = acc[e]; i1 = e; }
            float e1v = __expf(l1 - l0);
            float inv = 1.f / (1.f + e1v);
#pragma unroll
            for (int e = 0; e < NE; ++e) logits[(long)t * NE + e] = acc[e];
            aExp[tok * 2] = i0;     aW[tok * 2] = inv;
            aExp[tok * 2 + 1] = i1; aW[tok * 2 + 1] = e1v * inv;
        }
    }
    __syncthreads();

    if (threadIdx.x < NE) {
        const int e = threadIdx.x;
        int c = 0;
#pragma unroll
        for (int k = 0; k < 32; ++k) c += (aExp[k] == e);
        if (c) {
            int pos = atomicAdd(&cnt[e], c);
            for (int k = 0; k < 32; ++k)
                if (aExp[k] == e) {
                    list[e * T_TOK + pos] = blockIdx.x * 16 + (k >> 1);
                    wl[e * T_TOK + pos] = aW[k];
                    ++pos;
                }
        }
    }
}

// ---------------------------------------------------------------------------
// Kernel 3: grouped expert GEMM. 128x128 tile, BK=64, 4 waves of 4x4
// 16x16x32 bf16 MFMA (round-0 structure: fine granularity, 2176 working
// blocks), now DOUBLE-BUFFERED with counted-vmcnt prefetch:
//   boundary of tile t: issue tile t+1's 8 global_load_lds into buf^1,
//   then s_waitcnt vmcnt(8) -> only tile t's 8 loads drain; t+1's stay in
//   flight across the barrier and the whole compute phase. vmcnt never hits
//   0 in the main loop (T4). Old version drained vmcnt(0) every tile,
//   exposing the scattered token-gather latency 32x per block.
// LDS 65 KiB -> 2 blocks/CU (independent blocks overlap each other's
// barrier/boundary stalls; also the role-diversity that makes setprio pay).
// WAR: tile t's trailing barrier orders all waves' reads of buf b before
// tile t+1's boundary writes into buf b. RAW: boundary vmcnt + barrier.
// LDS layout XOR-swizzled as before: logical (row r, 16B-chunk c) at phys
// chunk (r<<3)|(c^(r&7)); global source pre-swizzled to match (involution).
// ---------------------------------------------------------------------------
__global__ __launch_bounds__(256, 2) void moe_gemm(
        const unsigned short* __restrict__ xb, const unsigned short* __restrict__ wb,
        const int* __restrict__ cnt, const int* __restrict__ list,
        const float* __restrict__ wl, float* __restrict__ out) {
    __shared__ uint4 As[2][1024];  // 2 x (128 rows x 64 bf16) = 32 KiB
    __shared__ uint4 Bs[2][1024];  // 32 KiB
    __shared__ int tIdx[128];
    __shared__ float tw[128];

    const int bx = blockIdx.x;
    const int e  = bx >> 10;         // 1024 blocks per expert
    const int rt = (bx >> 4) & 63;   // 64 row tiles
    const int ct = bx & 15;          // 16 col tiles (adjacent: share A-tile -> L2)
    const int n = cnt[e];
    const int row0 = rt << 7;
    if (row0 >= n) return;
    const int rv = min(128, n - row0);

    const int tid = threadIdx.x;
    if (tid < 128) {
        if (tid < rv) {
            tIdx[tid] = list[e * T_TOK + row0 + tid];
            tw[tid]   = wl[e * T_TOK + row0 + tid];
        } else { tIdx[tid] = 0; tw[tid] = 0.f; }
    }
    __syncthreads();

    const int wave = tid >> 6, lane = tid & 63;
    const int wm = (wave >> 1) << 6;   // 0 / 64
    const int wn = (wave & 1) << 6;    // 0 / 64
    const int quad = lane >> 4, l16 = lane & 15;

    f32x4 acc[4][4];
#pragma unroll
    for (int i = 0; i < 4; ++i)
#pragma unroll
        for (int j = 0; j < 4; ++j) acc[i][j] = (f32x4){0.f, 0.f, 0.f, 0.f};

    // Per-lane pre-swizzled global sources: phys chunk p = i*256 + wave*64 + lane
    const unsigned short* aSrc[4];
    const unsigned short* bSrc[4];
    const long wbase = (long)e * H_DIM * H_DIM + (long)(ct * 128) * H_DIM;
#pragma unroll
    for (int i = 0; i < 4; ++i) {
        const int p = i * 256 + tid;
        const int r = p >> 3;
        const int c = (p & 7) ^ (r & 7);   // logical k-chunk for this phys slot
        aSrc[i] = xb + (long)tIdx[r] * H_DIM + c * 8;
        bSrc[i] = wb + wbase + (long)r * H_DIM + c * 8;
    }
    const int dst0 = wave * 64;   // wave-uniform LDS chunk base within each issue

    // Prologue: stage tile 0 into buffer 0 (8 loads in flight).
#pragma unroll
    for (int i = 0; i < 4; ++i) async_ld16(aSrc[i], &As[0][i * 256 + dst0]);
#pragma unroll
    for (int i = 0; i < 4; ++i) async_ld16(bSrc[i], &Bs[0][i * 256 + dst0]);

#pragma unroll 2
    for (int t = 0; t < NT; ++t) {
        const int b = t & 1;

        // ---- boundary: prefetch tile t+1 into buf^1, counted wait on tile t
        if (t + 1 < NT) {
            const int k1 = (t + 1) << 6;
#pragma unroll
            for (int i = 0; i < 4; ++i)
                async_ld16(aSrc[i] + k1, &As[b ^ 1][i * 256 + dst0]);
#pragma unroll
            for (int i = 0; i < 4; ++i)
                async_ld16(bSrc[i] + k1, &Bs[b ^ 1][i * 256 + dst0]);
            asm volatile("s_waitcnt vmcnt(8)" ::: "memory");  // tile t retired
        } else {
            asm volatile("s_waitcnt vmcnt(0)" ::: "memory");  // last tile drain
        }
        __builtin_amdgcn_s_barrier();   // buf b valid for all waves

        // ---- compute on buf b
        const s16x8* Ap = (const s16x8*)&As[b][0];
        const s16x8* Bp = (const s16x8*)&Bs[b][0];
#pragma unroll
        for (int ks = 0; ks < 2; ++ks) {
            s16x8 af[4], bfr[4];
            const int kc = ks * 4 + quad;
#pragma unroll
            for (int i = 0; i < 4; ++i) {
                int r = wm + i * 16 + l16;
                af[i] = Ap[(r << 3) | (kc ^ (r & 7))];
            }
#pragma unroll
            for (int j = 0; j < 4; ++j) {
                int d = wn + j * 16 + l16;
                bfr[j] = Bp[(d << 3) | (kc ^ (d & 7))];
            }
            __builtin_amdgcn_s_setprio(1);
#pragma unroll
            for (int i = 0; i < 4; ++i)
#pragma unroll
                for (int j = 0; j < 4; ++j)
                    acc[i][j] = __builtin_amdgcn_mfma_f32_16x16x32_bf16(
                        af[i], bfr[j], acc[i][j], 0, 0, 0);
            __builtin_amdgcn_s_setprio(0);
        }
        __builtin_amdgcn_s_barrier();   // all reads of buf b done (WAR guard)
    }

    // Epilogue: C/D layout col = lane&15, row = quad*4 + reg. (unchanged)
    const int colbase = ct * 128 + wn;
#pragma unroll
    for (int i = 0; i < 4; ++i) {
        const int rbase = wm + i * 16 + quad * 4;
#pragma unroll
        for (int jr = 0; jr < 4; ++jr) {
            const int r = rbase + jr;
            if (r < rv) {
                const float wgt = tw[r];
                const long orow = (long)tIdx[r] * H_DIM + colbase;
#pragma unroll
                for (int j = 0; j < 4; ++j)
                    atomicAdd(&out[orow + j * 16 + l16], acc[i][j][jr] * wgt);
            }
        }
    }
}

// ---------------------------------------------------------------------------
extern "C" void kernel_launch(void* const* d_in, const int* in_sizes, int n_in,
                              void* d_out, int out_size, void* d_ws, size_t ws_size,
                              hipStream_t stream) {
    (void)in_sizes; (void)n_in; (void)out_size; (void)ws_size;
    const float* x    = (const float*)d_in[0];   // [T, H] fp32
    const float* gate = (const float*)d_in[1];   // [E, H] fp32
    const float* w    = (const float*)d_in[2];   // [E, H, H] fp32

    float* out    = (float*)d_out;                       // [T, H]
    float* logits = out + (size_t)T_TOK * H_DIM;         // [T, E]

    char* ws = (char*)d_ws;
    unsigned short* xb = (unsigned short*)(ws);                 // 33,554,432 B
    unsigned short* wb = (unsigned short*)(ws + 33554432);      // 67,108,864 B
    int*   cnt  = (int*)(ws + 100663296);                       // 32 B
    int*   list = (int*)(ws + 100663328);                       // 262,144 B
    float* wl   = (float*)(ws + 100925472);                     // 262,144 B

    hipMemsetAsync(out, 0, (size_t)T_TOK * H_DIM * sizeof(float), stream);
    prep_kernel<<<2048, 256, 0, stream>>>(w, wb, cnt);
    router_kernel<<<512, 256, 0, stream>>>(x, gate, xb, logits, cnt, list, wl);
    moe_gemm<<<8192, 256, 0, stream>>>(xb, wb, cnt, list, wl, out);
}